// Round 1
// baseline (245.145 us; speedup 1.0000x reference)
//
#include <hip/hip_runtime.h>

typedef __bf16 bf16_t;
typedef __attribute__((ext_vector_type(8))) __bf16 bf16x8;
typedef __attribute__((ext_vector_type(8))) unsigned short u16x8;
typedef __attribute__((ext_vector_type(4))) float f32x4;

#define MFMA(a, b, c) __builtin_amdgcn_mfma_f32_16x16x32_bf16((a), (b), (c), 0, 0, 0)

__device__ __forceinline__ float bf2f(unsigned short s) {
    unsigned u = ((unsigned)s) << 16;
    return __builtin_bit_cast(float, u);
}
__device__ __forceinline__ unsigned short f2bf(float f) {
    return __builtin_bit_cast(unsigned short, (bf16_t)f);
}

// ---------------------------------------------------------------------------
// prep: convert W1, W2, W3 to bf16 in chunked [cc][n][kk] layout in workspace
//   W1s: ws bf16 [0, 16384)   : W1s[cc*4096 + n*32 + kk] = W1[(cc*32+kk)*128 + n]
//   W2s: ws bf16 [16384,32768): same for W2
//   W3s: ws bf16 [32768,34816): W3s[o*128 + k] = W3[k*12+o] (o<12, else 0)
// ---------------------------------------------------------------------------
__global__ void inr_prep(const float* __restrict__ W1,
                         const float* __restrict__ W2,
                         const float* __restrict__ W3,
                         unsigned short* __restrict__ wsb)
{
    int idx = blockIdx.x * 256 + threadIdx.x;
    if (idx < 16384) {
        int cc = idx >> 12, rem = idx & 4095, n = rem >> 5, kk = rem & 31;
        wsb[idx] = f2bf(W1[(cc * 32 + kk) * 128 + n]);
    } else if (idx < 32768) {
        int j = idx - 16384;
        int cc = j >> 12, rem = j & 4095, n = rem >> 5, kk = rem & 31;
        wsb[idx] = f2bf(W2[(cc * 32 + kk) * 128 + n]);
    } else if (idx < 34816) {
        int r = idx - 32768;
        int o = r >> 7, k = r & 127;
        wsb[idx] = f2bf((o < 12) ? W3[k * 12 + o] : 0.f);
    }
}

// ---------------------------------------------------------------------------
// main fused kernel: 784 blocks x 256 threads; 64 points per block.
// ---------------------------------------------------------------------------
__global__ __launch_bounds__(256, 2)
void inr_main(const float* __restrict__ inp,
              const float* __restrict__ W0g,
              const float* __restrict__ b0g,
              const float* __restrict__ b1g,
              const float* __restrict__ b2g,
              const float* __restrict__ b3g,
              const bf16_t* __restrict__ wsb,
              float* __restrict__ out)
{
    __shared__ unsigned short h0buf[64][136];  // h0_base (pre-relu, +b0), bf16
    __shared__ unsigned short h1buf[64][136];  // h1 then h2, bf16
    __shared__ unsigned short Abuf[64][40];    // gathered A chunk [m][kk]
    __shared__ unsigned short Wbuf[128][40];   // W0 chunk [n][kk]
    __shared__ unsigned short W3buf[16][136];  // W3^T [o][k]
    __shared__ float ct4[4][128];              // per-iteration cell vectors

    const int tid  = threadIdx.x;
    const int lane = tid & 63;
    const int wave = tid >> 6;
    const int l15  = lane & 15;
    const int q    = lane >> 4;
    const int wm   = wave >> 1;   // m-half (0/1): rows wm*32..wm*32+31
    const int wn   = wave & 1;    // n-half (0/1): cols wn*64..wn*64+63
    const int tile = blockIdx.x;

    // ---- one-time staging: ct4 and W3buf ----
    if (tid < 128) {
        int k = tid;
        float wa = W0g[716 * 128 + k] + W0g[717 * 128 + k];
        float wb = W0g[718 * 128 + k] + W0g[719 * 128 + k];
        float p = 32.f;
        #pragma unroll
        for (int it = 0; it < 4; ++it) { ct4[it][k] = p * wa + wb; p *= 32.f; }
    }
    {
        int o = tid >> 4, kb = (tid & 15) * 8;
        bf16x8 wv = *(const bf16x8*)&wsb[32768 + o * 128 + kb];
        *(bf16x8*)&W3buf[o][kb] = wv;
    }

    // ---- per-lane constants ----
    float b0v[4], b1v[4], b2v[4];
    #pragma unroll
    for (int nb = 0; nb < 4; ++nb) {
        int col = wn * 64 + nb * 16 + l15;
        b0v[nb] = b0g[col]; b1v[nb] = b1g[col]; b2v[nb] = b2g[col];
    }
    float gln[2];
    #pragma unroll
    for (int mb = 0; mb < 2; ++mb) {
        int row = wm * 32 + mb * 16 + l15;
        int pp = ((tile & 15) << 6) + row;   // point index within its 1024-block
        gln[mb] = (pp < 2) ? 0.0625f : ((pp < 4) ? (2.f / 7.f) : 1.f);
    }

    // ---- gather-thread decode (point identity for the A gather) ----
    const int gm = tid & 63;     // point row in tile
    const int gw = tid >> 6;     // kk-group (tap within chunk)
    int n_g = tile * 64 + gm;
    int Bi = n_g >> 10, ppt = n_g & 1023;
    int u0 = Bi / 7, v0 = Bi - 7 * u0;
    int i0 = ppt >> 5, j0 = ppt & 31;

    const int cn = tid & 127;    // W-copy: output col
    const int chalf = tid >> 7;  // W-copy: kk half

    // ================= layer 0: H0 = q_feat @ W0p (+b0 later) =================
    f32x4 acc0[2][4];
    #pragma unroll
    for (int mb = 0; mb < 2; ++mb)
        #pragma unroll
        for (int nb = 0; nb < 4; ++nb)
            acc0[mb][nb] = (f32x4){0.f, 0.f, 0.f, 0.f};

    for (int cc = 0; cc < 21; ++cc) {
        // gather A chunk: k' = cc*32 + gw*8 + c ; f = c*81 + t ; t = cc*4+gw
        {
            int t = cc * 4 + gw;
            float vals[8];
            #pragma unroll
            for (int c = 0; c < 8; ++c) vals[c] = 0.f;
            if (t < 81) {
                int s = t / 9, a = t - 9 * s;
                int ki = s / 3, kj = s - 3 * ki, ku = a / 3, kv = a - 3 * ku;
                int uu = u0 + ku - 1, vv = v0 + kv - 1;
                int ii = i0 + ki - 1, jj = j0 + kj - 1;
                if ((unsigned)uu < 7u && (unsigned)vv < 7u &&
                    (unsigned)ii < 32u && (unsigned)jj < 32u) {
                    const float* p = inp + (((uu * 7 + vv) << 10) + (ii << 5) + jj);
                    #pragma unroll
                    for (int c = 0; c < 8; ++c) vals[c] = p[c * 50176];
                }
            }
            bf16x8 av;
            #pragma unroll
            for (int c = 0; c < 8; ++c) av[c] = (bf16_t)vals[c];
            *(bf16x8*)&Abuf[gm][gw * 8] = av;
        }
        // copy + permute W0 chunk: Wbuf[n][kk] = W0[f(k')][n]
        {
            bf16x8 wv0, wv1;
            #pragma unroll
            for (int e = 0; e < 16; ++e) {
                int kp = cc * 32 + chalf * 16 + e;
                float val = 0.f;
                if (kp < 648) {
                    int tt = kp >> 3, c = kp & 7;
                    val = W0g[(c * 81 + tt) * 128 + cn];
                }
                if (e < 8) wv0[e] = (bf16_t)val; else wv1[e - 8] = (bf16_t)val;
            }
            *(bf16x8*)&Wbuf[cn][chalf * 16] = wv0;
            *(bf16x8*)&Wbuf[cn][chalf * 16 + 8] = wv1;
        }
        __syncthreads();
        // MFMA: 2 m-blocks x 4 n-blocks per wave
        {
            bf16x8 af0 = *(const bf16x8*)&Abuf[wm * 32 + l15][q * 8];
            bf16x8 af1 = *(const bf16x8*)&Abuf[wm * 32 + 16 + l15][q * 8];
            #pragma unroll
            for (int nb = 0; nb < 4; ++nb) {
                bf16x8 wf = *(const bf16x8*)&Wbuf[wn * 64 + nb * 16 + l15][q * 8];
                acc0[0][nb] = MFMA(af0, wf, acc0[0][nb]);
                acc0[1][nb] = MFMA(af1, wf, acc0[1][nb]);
            }
        }
        __syncthreads();
    }

    // h0_base = acc0 + b0 -> bf16 LDS
    #pragma unroll
    for (int mb = 0; mb < 2; ++mb)
        #pragma unroll
        for (int nb = 0; nb < 4; ++nb) {
            int col = wn * 64 + nb * 16 + l15;
            #pragma unroll
            for (int r = 0; r < 4; ++r)
                h0buf[wm * 32 + mb * 16 + q * 4 + r][col] = f2bf(acc0[mb][nb][r] + b0v[nb]);
        }
    __syncthreads();

    // ================= 4 iterations of the 3 remaining layers =================
    f32x4 outacc = (f32x4){0.f, 0.f, 0.f, 0.f};
    const bf16x8* W1s8 = (const bf16x8*)&wsb[0];
    const bf16x8* W2s8 = (const bf16x8*)&wsb[16384];

    for (int it = 0; it < 4; ++it) {
        // ---- layer 1: A = relu(h0 + g*ct_it) built on the fly ----
        f32x4 acc1[2][4];
        #pragma unroll
        for (int mb = 0; mb < 2; ++mb)
            #pragma unroll
            for (int nb = 0; nb < 4; ++nb) acc1[mb][nb] = (f32x4){0.f, 0.f, 0.f, 0.f};

        #pragma unroll
        for (int cc = 0; cc < 4; ++cc) {
            int k0 = cc * 32 + q * 8;
            f32x4 ct0 = *(const f32x4*)&ct4[it][k0];
            f32x4 ct1 = *(const f32x4*)&ct4[it][k0 + 4];
            bf16x8 wf[4];
            #pragma unroll
            for (int nb = 0; nb < 4; ++nb)
                wf[nb] = W1s8[cc * 512 + (wn * 64 + nb * 16 + l15) * 4 + q];
            #pragma unroll
            for (int mb = 0; mb < 2; ++mb) {
                u16x8 hv = *(const u16x8*)&h0buf[wm * 32 + mb * 16 + l15][k0];
                float g = gln[mb];
                bf16x8 af;
                #pragma unroll
                for (int e = 0; e < 8; ++e) {
                    float ctv = (e < 4) ? ct0[e] : ct1[e - 4];
                    float x = bf2f(hv[e]) + g * ctv;
                    af[e] = (bf16_t)fmaxf(x, 0.f);
                }
                #pragma unroll
                for (int nb = 0; nb < 4; ++nb)
                    acc1[mb][nb] = MFMA(af, wf[nb], acc1[mb][nb]);
            }
        }
        // h1 = relu(acc1 + b1) -> h1buf
        #pragma unroll
        for (int mb = 0; mb < 2; ++mb)
            #pragma unroll
            for (int nb = 0; nb < 4; ++nb) {
                int col = wn * 64 + nb * 16 + l15;
                #pragma unroll
                for (int r = 0; r < 4; ++r)
                    h1buf[wm * 32 + mb * 16 + q * 4 + r][col] =
                        f2bf(fmaxf(acc1[mb][nb][r] + b1v[nb], 0.f));
            }
        __syncthreads();

        // ---- layer 2 ----
        f32x4 acc2[2][4];
        #pragma unroll
        for (int mb = 0; mb < 2; ++mb)
            #pragma unroll
            for (int nb = 0; nb < 4; ++nb) acc2[mb][nb] = (f32x4){0.f, 0.f, 0.f, 0.f};

        #pragma unroll
        for (int cc = 0; cc < 4; ++cc) {
            int k0 = cc * 32 + q * 8;
            bf16x8 wf[4];
            #pragma unroll
            for (int nb = 0; nb < 4; ++nb)
                wf[nb] = W2s8[cc * 512 + (wn * 64 + nb * 16 + l15) * 4 + q];
            #pragma unroll
            for (int mb = 0; mb < 2; ++mb) {
                bf16x8 af = *(const bf16x8*)&h1buf[wm * 32 + mb * 16 + l15][k0];
                #pragma unroll
                for (int nb = 0; nb < 4; ++nb)
                    acc2[mb][nb] = MFMA(af, wf[nb], acc2[mb][nb]);
            }
        }
        __syncthreads();  // all h1 reads done before overwrite

        // h2 = relu(acc2 + b2) -> h1buf (reuse)
        #pragma unroll
        for (int mb = 0; mb < 2; ++mb)
            #pragma unroll
            for (int nb = 0; nb < 4; ++nb) {
                int col = wn * 64 + nb * 16 + l15;
                #pragma unroll
                for (int r = 0; r < 4; ++r)
                    h1buf[wm * 32 + mb * 16 + q * 4 + r][col] =
                        f2bf(fmaxf(acc2[mb][nb][r] + b2v[nb], 0.f));
            }
        __syncthreads();

        // ---- layer 3: wave m-split (16 rows each), N=16 (12 used) ----
        #pragma unroll
        for (int cc = 0; cc < 4; ++cc) {
            int k0 = cc * 32 + q * 8;
            bf16x8 af = *(const bf16x8*)&h1buf[wave * 16 + l15][k0];
            bf16x8 wf = *(const bf16x8*)&W3buf[l15][k0];
            outacc = MFMA(af, wf, outacc);   // accumulates across cc AND iterations
        }
        __syncthreads();  // protect h1buf for next iteration's L1 write
    }

    // ================= epilogue: 0.25*sum + b3, pixel-shuffle scatter =========
    {
        int o = l15;
        if (o < 12) {
            float b3v = b3g[o];
            int ch = o >> 2, s = (o >> 1) & 1, t2 = o & 1;
            #pragma unroll
            for (int r = 0; r < 4; ++r) {
                int m = wave * 16 + q * 4 + r;
                int ng = tile * 64 + m;
                int B2 = ng >> 10, pq = ng & 1023;
                int u2 = B2 / 7, v2 = B2 - 7 * u2;
                int i2 = pq >> 5, j2 = pq & 31;
                float val = 0.25f * outacc[r] + b3v;
                out[((ch * 7 + u2) * 7 + v2) * 4096 + (2 * i2 + s) * 64 + (2 * j2 + t2)] = val;
            }
        }
    }
}

extern "C" void kernel_launch(void* const* d_in, const int* in_sizes, int n_in,
                              void* d_out, int out_size, void* d_ws, size_t ws_size,
                              hipStream_t stream)
{
    (void)in_sizes; (void)n_in; (void)out_size; (void)ws_size;
    const float* inp = (const float*)d_in[0];
    const float* W0  = (const float*)d_in[1];
    const float* b0  = (const float*)d_in[2];
    const float* W1  = (const float*)d_in[3];
    const float* b1  = (const float*)d_in[4];
    const float* W2  = (const float*)d_in[5];
    const float* b2  = (const float*)d_in[6];
    const float* W3  = (const float*)d_in[7];
    const float* b3  = (const float*)d_in[8];
    float* out = (float*)d_out;
    unsigned short* wsb = (unsigned short*)d_ws;

    inr_prep<<<136, 256, 0, stream>>>(W1, W2, W3, wsb);
    inr_main<<<784, 256, 0, stream>>>(inp, W0, b0, b1, b2, b3, (const bf16_t*)wsb, out);
}

// Round 2
// 167.125 us; speedup vs baseline: 1.4668x; 1.4668x over previous
//
#include <hip/hip_runtime.h>

typedef __bf16 bf16_t;
typedef __attribute__((ext_vector_type(8))) __bf16 bf16x8;
typedef __attribute__((ext_vector_type(8))) unsigned short u16x8;
typedef __attribute__((ext_vector_type(4))) float f32x4;

#define MFMA(a, b, c) __builtin_amdgcn_mfma_f32_16x16x32_bf16((a), (b), (c), 0, 0, 0)

__device__ __forceinline__ float bf2f(unsigned short s) {
    unsigned u = ((unsigned)s) << 16;
    return __builtin_bit_cast(float, u);
}
__device__ __forceinline__ unsigned short f2bf(float f) {
    return __builtin_bit_cast(unsigned short, (bf16_t)f);
}

// ---------------------------------------------------------------------------
// prep: convert all weights to bf16 MFMA-ready layouts in workspace (shorts):
//   W1s: [0,16384)        : W1s[cc*4096 + n*32 + kk] = W1[(cc*32+kk)*128 + n]
//   W2s: [16384,32768)    : same for W2
//   W3s: [32768,34816)    : W3s[o*128 + k] = W3[k*12+o] (o<12, else 0)
//   W0s: [34816,120832)   : W0s[cc*4096 + n*32 + kk] = W0[f(k')][n],
//                           k'=cc*32+kk, f=(k'&7)*81+(k'>>3), 0 if k'>=648
// ---------------------------------------------------------------------------
__global__ void inr_prep(const float* __restrict__ W0,
                         const float* __restrict__ W1,
                         const float* __restrict__ W2,
                         const float* __restrict__ W3,
                         unsigned short* __restrict__ wsb)
{
    int idx = blockIdx.x * 256 + threadIdx.x;
    if (idx < 16384) {
        int cc = idx >> 12, rem = idx & 4095, n = rem >> 5, kk = rem & 31;
        wsb[idx] = f2bf(W1[(cc * 32 + kk) * 128 + n]);
    } else if (idx < 32768) {
        int j = idx - 16384;
        int cc = j >> 12, rem = j & 4095, n = rem >> 5, kk = rem & 31;
        wsb[idx] = f2bf(W2[(cc * 32 + kk) * 128 + n]);
    } else if (idx < 34816) {
        int r = idx - 32768;
        int o = r >> 7, k = r & 127;
        wsb[idx] = f2bf((o < 12) ? W3[k * 12 + o] : 0.f);
    } else if (idx < 120832) {
        int j = idx - 34816;
        int cc = j >> 12, rem = j & 4095, n = rem >> 5, kk = rem & 31;
        int kp = cc * 32 + kk;
        float val = 0.f;
        if (kp < 648) {
            int tt = kp >> 3, c = kp & 7;
            val = W0[(c * 81 + tt) * 128 + n];
        }
        wsb[idx] = f2bf(val);
    }
}

// ---------------------------------------------------------------------------
// main fused kernel: 784 blocks x 256 threads; 64 points per block.
// Wave grid 2x2: wave (wm,wn) computes rows wm*32..+31, cols wn*64..+63.
// Layer 0 is barrier-free: A-frags register-gathered, W0-frags direct global.
// ---------------------------------------------------------------------------
__global__ __launch_bounds__(256, 3)
void inr_main(const float* __restrict__ inp,
              const float* __restrict__ W0g,
              const float* __restrict__ b0g,
              const float* __restrict__ b1g,
              const float* __restrict__ b2g,
              const float* __restrict__ b3g,
              const bf16_t* __restrict__ wsb,
              float* __restrict__ out)
{
    __shared__ unsigned short h0buf[64][136];  // h0_base (pre-relu, +b0), bf16
    __shared__ unsigned short h1buf[64][136];  // h1 then h2, bf16
    __shared__ float ct4[4][128];              // per-iteration cell vectors

    const int tid  = threadIdx.x;
    const int lane = tid & 63;
    const int wave = tid >> 6;
    const int l15  = lane & 15;
    const int q    = lane >> 4;
    const int wm   = wave >> 1;   // m-half (0/1)
    const int wn   = wave & 1;    // n-half (0/1)
    const int tile = blockIdx.x;

    // ---- one-time staging: ct4 (read after the post-h0 barrier) ----
    if (tid < 128) {
        int k = tid;
        float wa = W0g[716 * 128 + k] + W0g[717 * 128 + k];
        float wb = W0g[718 * 128 + k] + W0g[719 * 128 + k];
        float p = 32.f;
        #pragma unroll
        for (int it = 0; it < 4; ++it) { ct4[it][k] = p * wa + wb; p *= 32.f; }
    }

    // ---- per-lane constants ----
    float b0v[4], b1v[4], b2v[4];
    #pragma unroll
    for (int nb = 0; nb < 4; ++nb) {
        int col = wn * 64 + nb * 16 + l15;
        b0v[nb] = b0g[col]; b1v[nb] = b1g[col]; b2v[nb] = b2g[col];
    }
    float gln[2];
    #pragma unroll
    for (int mb = 0; mb < 2; ++mb) {
        int row = wm * 32 + mb * 16 + l15;
        int pp = ((tile & 15) << 6) + row;
        gln[mb] = (pp < 2) ? 0.0625f : ((pp < 4) ? (2.f / 7.f) : 1.f);
    }

    // ---- point decode for the register A-gather (2 rows per lane) ----
    int u0[2], v0[2], i0[2], j0[2];
    #pragma unroll
    for (int mb = 0; mb < 2; ++mb) {
        int n_g = tile * 64 + wm * 32 + mb * 16 + l15;
        int Bi = n_g >> 10, ppt = n_g & 1023;
        u0[mb] = Bi / 7; v0[mb] = Bi - 7 * u0[mb];
        i0[mb] = ppt >> 5; j0[mb] = ppt & 31;
    }

    const bf16x8* W0s8 = (const bf16x8*)&wsb[34816];
    const bf16x8* W1s8 = (const bf16x8*)&wsb[0];
    const bf16x8* W2s8 = (const bf16x8*)&wsb[16384];
    const bf16x8* W3s8 = (const bf16x8*)&wsb[32768];

    // ================= layer 0: barrier-free K-loop =================
    f32x4 acc0[2][4];
    #pragma unroll
    for (int mb = 0; mb < 2; ++mb)
        #pragma unroll
        for (int nb = 0; nb < 4; ++nb)
            acc0[mb][nb] = (f32x4){0.f, 0.f, 0.f, 0.f};

    for (int cc = 0; cc < 21; ++cc) {
        // W0 frags direct from global (L2-resident bf16 panel)
        bf16x8 wf[4];
        #pragma unroll
        for (int nb = 0; nb < 4; ++nb)
            wf[nb] = W0s8[cc * 512 + (wn * 64 + nb * 16 + l15) * 4 + q];

        // tap decode (shared by both m-blocks)
        int t = cc * 4 + q;
        int s = t / 9, a = t - 9 * s;
        int ki = s / 3, kj = s - 3 * ki, ku = a / 3, kv = a - 3 * ku;
        bool tap_ok = (t < 81);

        #pragma unroll
        for (int mb = 0; mb < 2; ++mb) {
            float vals[8];
            #pragma unroll
            for (int c = 0; c < 8; ++c) vals[c] = 0.f;
            int uu = u0[mb] + ku - 1, vv = v0[mb] + kv - 1;
            int ii = i0[mb] + ki - 1, jj = j0[mb] + kj - 1;
            if (tap_ok && (unsigned)uu < 7u && (unsigned)vv < 7u &&
                (unsigned)ii < 32u && (unsigned)jj < 32u) {
                const float* p = inp + (((uu * 7 + vv) << 10) + (ii << 5) + jj);
                #pragma unroll
                for (int c = 0; c < 8; ++c) vals[c] = p[c * 50176];
            }
            bf16x8 af;
            #pragma unroll
            for (int c = 0; c < 8; ++c) af[c] = (bf16_t)vals[c];
            #pragma unroll
            for (int nb = 0; nb < 4; ++nb)
                acc0[mb][nb] = MFMA(af, wf[nb], acc0[mb][nb]);
        }
    }

    // h0_base = acc0 + b0 -> bf16 LDS
    #pragma unroll
    for (int mb = 0; mb < 2; ++mb)
        #pragma unroll
        for (int nb = 0; nb < 4; ++nb) {
            int col = wn * 64 + nb * 16 + l15;
            #pragma unroll
            for (int r = 0; r < 4; ++r)
                h0buf[wm * 32 + mb * 16 + q * 4 + r][col] = f2bf(acc0[mb][nb][r] + b0v[nb]);
        }
    __syncthreads();

    // ================= 4 iterations of the 3 remaining layers =================
    f32x4 outacc = (f32x4){0.f, 0.f, 0.f, 0.f};

    for (int it = 0; it < 4; ++it) {
        // ---- layer 1: A = relu(h0 + g*ct_it) built on the fly ----
        f32x4 acc1[2][4];
        #pragma unroll
        for (int mb = 0; mb < 2; ++mb)
            #pragma unroll
            for (int nb = 0; nb < 4; ++nb) acc1[mb][nb] = (f32x4){0.f, 0.f, 0.f, 0.f};

        #pragma unroll
        for (int cc = 0; cc < 4; ++cc) {
            int k0 = cc * 32 + q * 8;
            f32x4 ct0 = *(const f32x4*)&ct4[it][k0];
            f32x4 ct1 = *(const f32x4*)&ct4[it][k0 + 4];
            bf16x8 wf[4];
            #pragma unroll
            for (int nb = 0; nb < 4; ++nb)
                wf[nb] = W1s8[cc * 512 + (wn * 64 + nb * 16 + l15) * 4 + q];
            #pragma unroll
            for (int mb = 0; mb < 2; ++mb) {
                u16x8 hv = *(const u16x8*)&h0buf[wm * 32 + mb * 16 + l15][k0];
                float g = gln[mb];
                bf16x8 af;
                #pragma unroll
                for (int e = 0; e < 8; ++e) {
                    float ctv = (e < 4) ? ct0[e] : ct1[e - 4];
                    float x = bf2f(hv[e]) + g * ctv;
                    af[e] = (bf16_t)fmaxf(x, 0.f);
                }
                #pragma unroll
                for (int nb = 0; nb < 4; ++nb)
                    acc1[mb][nb] = MFMA(af, wf[nb], acc1[mb][nb]);
            }
        }
        // h1 = relu(acc1 + b1) -> h1buf
        #pragma unroll
        for (int mb = 0; mb < 2; ++mb)
            #pragma unroll
            for (int nb = 0; nb < 4; ++nb) {
                int col = wn * 64 + nb * 16 + l15;
                #pragma unroll
                for (int r = 0; r < 4; ++r)
                    h1buf[wm * 32 + mb * 16 + q * 4 + r][col] =
                        f2bf(fmaxf(acc1[mb][nb][r] + b1v[nb], 0.f));
            }
        __syncthreads();

        // ---- layer 2 ----
        f32x4 acc2[2][4];
        #pragma unroll
        for (int mb = 0; mb < 2; ++mb)
            #pragma unroll
            for (int nb = 0; nb < 4; ++nb) acc2[mb][nb] = (f32x4){0.f, 0.f, 0.f, 0.f};

        #pragma unroll
        for (int cc = 0; cc < 4; ++cc) {
            int k0 = cc * 32 + q * 8;
            bf16x8 wf[4];
            #pragma unroll
            for (int nb = 0; nb < 4; ++nb)
                wf[nb] = W2s8[cc * 512 + (wn * 64 + nb * 16 + l15) * 4 + q];
            #pragma unroll
            for (int mb = 0; mb < 2; ++mb) {
                bf16x8 af = *(const bf16x8*)&h1buf[wm * 32 + mb * 16 + l15][k0];
                #pragma unroll
                for (int nb = 0; nb < 4; ++nb)
                    acc2[mb][nb] = MFMA(af, wf[nb], acc2[mb][nb]);
            }
        }
        __syncthreads();  // all h1 reads done before overwrite

        // h2 = relu(acc2 + b2) -> h1buf (reuse)
        #pragma unroll
        for (int mb = 0; mb < 2; ++mb)
            #pragma unroll
            for (int nb = 0; nb < 4; ++nb) {
                int col = wn * 64 + nb * 16 + l15;
                #pragma unroll
                for (int r = 0; r < 4; ++r)
                    h1buf[wm * 32 + mb * 16 + q * 4 + r][col] =
                        f2bf(fmaxf(acc2[mb][nb][r] + b2v[nb], 0.f));
            }
        __syncthreads();

        // ---- layer 3: wave m-split (16 rows each), W3 frags direct global ----
        #pragma unroll
        for (int cc = 0; cc < 4; ++cc) {
            int k0 = cc * 32 + q * 8;
            bf16x8 af = *(const bf16x8*)&h1buf[wave * 16 + l15][k0];
            bf16x8 wf = W3s8[l15 * 16 + cc * 4 + q];
            outacc = MFMA(af, wf, outacc);   // accumulates across cc AND iterations
        }
        __syncthreads();  // protect h1buf for next iteration's L1 write
    }

    // ================= epilogue: 0.25*sum + b3, pixel-shuffle scatter =========
    {
        int o = l15;
        if (o < 12) {
            float b3v = b3g[o];
            int ch = o >> 2, s = (o >> 1) & 1, t2 = o & 1;
            #pragma unroll
            for (int r = 0; r < 4; ++r) {
                int m = wave * 16 + q * 4 + r;
                int ng = tile * 64 + m;
                int B2 = ng >> 10, pq = ng & 1023;
                int u2 = B2 / 7, v2 = B2 - 7 * u2;
                int i2 = pq >> 5, j2 = pq & 31;
                float val = 0.25f * outacc[r] + b3v;
                out[((ch * 7 + u2) * 7 + v2) * 4096 + (2 * i2 + s) * 64 + (2 * j2 + t2)] = val;
            }
        }
    }
}

extern "C" void kernel_launch(void* const* d_in, const int* in_sizes, int n_in,
                              void* d_out, int out_size, void* d_ws, size_t ws_size,
                              hipStream_t stream)
{
    (void)in_sizes; (void)n_in; (void)out_size; (void)ws_size;
    const float* inp = (const float*)d_in[0];
    const float* W0  = (const float*)d_in[1];
    const float* b0  = (const float*)d_in[2];
    const float* W1  = (const float*)d_in[3];
    const float* b1  = (const float*)d_in[4];
    const float* W2  = (const float*)d_in[5];
    const float* b2  = (const float*)d_in[6];
    const float* W3  = (const float*)d_in[7];
    const float* b3  = (const float*)d_in[8];
    float* out = (float*)d_out;
    unsigned short* wsb = (unsigned short*)d_ws;

    inr_prep<<<472, 256, 0, stream>>>(W0, W1, W2, W3, wsb);
    inr_main<<<784, 256, 0, stream>>>(inp, W0, b0, b1, b2, b3, (const bf16_t*)wsb, out);
}

// Round 3
// 166.737 us; speedup vs baseline: 1.4703x; 1.0023x over previous
//
#include <hip/hip_runtime.h>

typedef __bf16 bf16_t;
typedef __attribute__((ext_vector_type(8))) __bf16 bf16x8;
typedef __attribute__((ext_vector_type(8))) unsigned short u16x8;
typedef __attribute__((ext_vector_type(4))) float f32x4;

#define MFMA(a, b, c) __builtin_amdgcn_mfma_f32_16x16x32_bf16((a), (b), (c), 0, 0, 0)

__device__ __forceinline__ float bf2f(unsigned short s) {
    unsigned u = ((unsigned)s) << 16;
    return __builtin_bit_cast(float, u);
}
__device__ __forceinline__ unsigned short f2bf(float f) {
    return __builtin_bit_cast(unsigned short, (bf16_t)f);
}

// ---------------------------------------------------------------------------
// ws layout (unsigned short elements):
//   W1s: [0,16384)         W1s[cc*4096 + n*32 + kk] = W1[(cc*32+kk)*128 + n]
//   W2s: [16384,32768)     same for W2
//   W3s: [32768,34816)     W3s[o*128 + k] = W3[k*12+o] (o<12, else 0)
//   W0s: [34816,120832)    W0s[cc*4096 + n*32 + kk] = W0[f(k')][n],
//                          k'=cc*32+kk, f=(k'&7)*81+(k'>>3), 0 if k'>=648
//   inp_bf: [120832,522240) channel-last bf16: inp_bf[p*8+c] = inp[c*50176+p]
// ---------------------------------------------------------------------------
__global__ void inr_prep(const float* __restrict__ inp,
                         const float* __restrict__ W0,
                         const float* __restrict__ W1,
                         const float* __restrict__ W2,
                         const float* __restrict__ W3,
                         unsigned short* __restrict__ wsb)
{
    int idx = blockIdx.x * 256 + threadIdx.x;
    if (idx < 16384) {
        int cc = idx >> 12, rem = idx & 4095, n = rem >> 5, kk = rem & 31;
        wsb[idx] = f2bf(W1[(cc * 32 + kk) * 128 + n]);
    } else if (idx < 32768) {
        int j = idx - 16384;
        int cc = j >> 12, rem = j & 4095, n = rem >> 5, kk = rem & 31;
        wsb[idx] = f2bf(W2[(cc * 32 + kk) * 128 + n]);
    } else if (idx < 34816) {
        int r = idx - 32768;
        int o = r >> 7, k = r & 127;
        wsb[idx] = f2bf((o < 12) ? W3[k * 12 + o] : 0.f);
    } else if (idx < 120832) {
        int j = idx - 34816;
        int cc = j >> 12, rem = j & 4095, n = rem >> 5, kk = rem & 31;
        int kp = cc * 32 + kk;
        float val = 0.f;
        if (kp < 648) {
            int tt = kp >> 3, c = kp & 7;
            val = W0[(c * 81 + tt) * 128 + n];
        }
        wsb[idx] = f2bf(val);
    } else if (idx < 171008) {
        int p = idx - 120832;               // point 0..50175
        const float* src = inp + p;
        bf16x8 v;
        #pragma unroll
        for (int c = 0; c < 8; ++c) v[c] = (bf16_t)src[c * 50176];
        *(bf16x8*)&wsb[120832 + p * 8] = v;
    }
}

// ---------------------------------------------------------------------------
// main fused kernel: 784 blocks x 256 threads; 64 points per block.
// Wave grid 2x2: wave (wm,wn) computes rows wm*32..+31, cols wn*64..+63.
// Tile id is XCD-swizzled so each XCD sees 98 consecutive tiles (L2 reuse).
// ---------------------------------------------------------------------------
__global__ __launch_bounds__(256, 3)
void inr_main(const float* __restrict__ W0g,
              const float* __restrict__ b0g,
              const float* __restrict__ b1g,
              const float* __restrict__ b2g,
              const float* __restrict__ b3g,
              const bf16_t* __restrict__ wsb,
              float* __restrict__ out)
{
    __shared__ unsigned short h0buf[64][136];  // h0_base (pre-relu, +b0), bf16
    __shared__ unsigned short h1buf[64][136];  // h1 then h2, bf16
    __shared__ float ct4[4][128];              // per-iteration cell vectors

    const int tid  = threadIdx.x;
    const int lane = tid & 63;
    const int wave = tid >> 6;
    const int l15  = lane & 15;
    const int q    = lane >> 4;
    const int wm   = wave >> 1;   // m-half (0/1)
    const int wn   = wave & 1;    // n-half (0/1)
    // XCD-locality swizzle: blocks with blockIdx%8==g (same XCD under round-
    // robin dispatch) process tiles [g*98,(g+1)*98) in order -> gather region
    // stays L2-resident per XCD.
    const int tile = (blockIdx.x & 7) * 98 + (blockIdx.x >> 3);

    // ---- one-time staging: ct4 (read after the post-h0 barrier) ----
    if (tid < 128) {
        int k = tid;
        float wa = W0g[716 * 128 + k] + W0g[717 * 128 + k];
        float wb = W0g[718 * 128 + k] + W0g[719 * 128 + k];
        float p = 32.f;
        #pragma unroll
        for (int it = 0; it < 4; ++it) { ct4[it][k] = p * wa + wb; p *= 32.f; }
    }

    // ---- per-lane constants ----
    float b0v[4], b1v[4], b2v[4];
    #pragma unroll
    for (int nb = 0; nb < 4; ++nb) {
        int col = wn * 64 + nb * 16 + l15;
        b0v[nb] = b0g[col]; b1v[nb] = b1g[col]; b2v[nb] = b2g[col];
    }
    float gln[2];
    #pragma unroll
    for (int mb = 0; mb < 2; ++mb) {
        int row = wm * 32 + mb * 16 + l15;
        int pp = ((tile & 15) << 6) + row;
        gln[mb] = (pp < 2) ? 0.0625f : ((pp < 4) ? (2.f / 7.f) : 1.f);
    }

    // ---- point decode for the register A-gather (2 rows per lane) ----
    int u0[2], v0[2], i0[2], j0[2];
    #pragma unroll
    for (int mb = 0; mb < 2; ++mb) {
        int n_g = tile * 64 + wm * 32 + mb * 16 + l15;
        int Bi = n_g >> 10, ppt = n_g & 1023;
        u0[mb] = Bi / 7; v0[mb] = Bi - 7 * u0[mb];
        i0[mb] = ppt >> 5; j0[mb] = ppt & 31;
    }

    const bf16x8* W0s8 = (const bf16x8*)&wsb[34816];
    const bf16x8* W1s8 = (const bf16x8*)&wsb[0];
    const bf16x8* W2s8 = (const bf16x8*)&wsb[16384];
    const bf16x8* W3s8 = (const bf16x8*)&wsb[32768];
    const bf16x8* inpb8 = (const bf16x8*)&wsb[120832];  // [plane_point][8ch]

    // ================= layer 0: barrier-free K-loop =================
    f32x4 acc0[2][4];
    #pragma unroll
    for (int mb = 0; mb < 2; ++mb)
        #pragma unroll
        for (int nb = 0; nb < 4; ++nb)
            acc0[mb][nb] = (f32x4){0.f, 0.f, 0.f, 0.f};

    for (int cc = 0; cc < 21; ++cc) {
        // W0 frags direct from global (L2-resident bf16 panel)
        bf16x8 wf[4];
        #pragma unroll
        for (int nb = 0; nb < 4; ++nb)
            wf[nb] = W0s8[cc * 512 + (wn * 64 + nb * 16 + l15) * 4 + q];

        // tap decode (per q)
        int t = cc * 4 + q;
        int s = t / 9, a = t - 9 * s;
        int ki = s / 3, kj = s - 3 * ki, ku = a / 3, kv = a - 3 * ku;
        bool tap_ok = (t < 81);

        #pragma unroll
        for (int mb = 0; mb < 2; ++mb) {
            int uu = u0[mb] + ku - 1, vv = v0[mb] + kv - 1;
            int ii = i0[mb] + ki - 1, jj = j0[mb] + kj - 1;
            bf16x8 af;
            #pragma unroll
            for (int e = 0; e < 8; ++e) af[e] = (bf16_t)0.f;
            if (tap_ok && (unsigned)uu < 7u && (unsigned)vv < 7u &&
                (unsigned)ii < 32u && (unsigned)jj < 32u) {
                af = inpb8[((uu * 7 + vv) << 10) + (ii << 5) + jj];  // 16B, 8 ch
            }
            #pragma unroll
            for (int nb = 0; nb < 4; ++nb)
                acc0[mb][nb] = MFMA(af, wf[nb], acc0[mb][nb]);
        }
    }

    // h0_base = acc0 + b0 -> bf16 LDS
    #pragma unroll
    for (int mb = 0; mb < 2; ++mb)
        #pragma unroll
        for (int nb = 0; nb < 4; ++nb) {
            int col = wn * 64 + nb * 16 + l15;
            #pragma unroll
            for (int r = 0; r < 4; ++r)
                h0buf[wm * 32 + mb * 16 + q * 4 + r][col] = f2bf(acc0[mb][nb][r] + b0v[nb]);
        }
    __syncthreads();

    // ================= 4 iterations of the 3 remaining layers =================
    f32x4 outacc = (f32x4){0.f, 0.f, 0.f, 0.f};

    for (int it = 0; it < 4; ++it) {
        // ---- layer 1: A = relu(h0 + g*ct_it) built on the fly ----
        f32x4 acc1[2][4];
        #pragma unroll
        for (int mb = 0; mb < 2; ++mb)
            #pragma unroll
            for (int nb = 0; nb < 4; ++nb) acc1[mb][nb] = (f32x4){0.f, 0.f, 0.f, 0.f};

        #pragma unroll
        for (int cc = 0; cc < 4; ++cc) {
            int k0 = cc * 32 + q * 8;
            f32x4 ct0 = *(const f32x4*)&ct4[it][k0];
            f32x4 ct1 = *(const f32x4*)&ct4[it][k0 + 4];
            bf16x8 wf[4];
            #pragma unroll
            for (int nb = 0; nb < 4; ++nb)
                wf[nb] = W1s8[cc * 512 + (wn * 64 + nb * 16 + l15) * 4 + q];
            #pragma unroll
            for (int mb = 0; mb < 2; ++mb) {
                u16x8 hv = *(const u16x8*)&h0buf[wm * 32 + mb * 16 + l15][k0];
                float g = gln[mb];
                bf16x8 af;
                #pragma unroll
                for (int e = 0; e < 8; ++e) {
                    float ctv = (e < 4) ? ct0[e] : ct1[e - 4];
                    float x = bf2f(hv[e]) + g * ctv;
                    af[e] = (bf16_t)fmaxf(x, 0.f);
                }
                #pragma unroll
                for (int nb = 0; nb < 4; ++nb)
                    acc1[mb][nb] = MFMA(af, wf[nb], acc1[mb][nb]);
            }
        }
        // h1 = relu(acc1 + b1) -> h1buf
        #pragma unroll
        for (int mb = 0; mb < 2; ++mb)
            #pragma unroll
            for (int nb = 0; nb < 4; ++nb) {
                int col = wn * 64 + nb * 16 + l15;
                #pragma unroll
                for (int r = 0; r < 4; ++r)
                    h1buf[wm * 32 + mb * 16 + q * 4 + r][col] =
                        f2bf(fmaxf(acc1[mb][nb][r] + b1v[nb], 0.f));
            }
        __syncthreads();

        // ---- layer 2 ----
        f32x4 acc2[2][4];
        #pragma unroll
        for (int mb = 0; mb < 2; ++mb)
            #pragma unroll
            for (int nb = 0; nb < 4; ++nb) acc2[mb][nb] = (f32x4){0.f, 0.f, 0.f, 0.f};

        #pragma unroll
        for (int cc = 0; cc < 4; ++cc) {
            int k0 = cc * 32 + q * 8;
            bf16x8 wf[4];
            #pragma unroll
            for (int nb = 0; nb < 4; ++nb)
                wf[nb] = W2s8[cc * 512 + (wn * 64 + nb * 16 + l15) * 4 + q];
            #pragma unroll
            for (int mb = 0; mb < 2; ++mb) {
                bf16x8 af = *(const bf16x8*)&h1buf[wm * 32 + mb * 16 + l15][k0];
                #pragma unroll
                for (int nb = 0; nb < 4; ++nb)
                    acc2[mb][nb] = MFMA(af, wf[nb], acc2[mb][nb]);
            }
        }
        __syncthreads();  // all h1 reads done before overwrite

        // h2 = relu(acc2 + b2) -> h1buf (reuse)
        #pragma unroll
        for (int mb = 0; mb < 2; ++mb)
            #pragma unroll
            for (int nb = 0; nb < 4; ++nb) {
                int col = wn * 64 + nb * 16 + l15;
                #pragma unroll
                for (int r = 0; r < 4; ++r)
                    h1buf[wm * 32 + mb * 16 + q * 4 + r][col] =
                        f2bf(fmaxf(acc2[mb][nb][r] + b2v[nb], 0.f));
            }
        __syncthreads();

        // ---- layer 3: wave m-split (16 rows each), W3 frags direct global ----
        #pragma unroll
        for (int cc = 0; cc < 4; ++cc) {
            int k0 = cc * 32 + q * 8;
            bf16x8 af = *(const bf16x8*)&h1buf[wave * 16 + l15][k0];
            bf16x8 wf = W3s8[l15 * 16 + cc * 4 + q];
            outacc = MFMA(af, wf, outacc);   // accumulates across cc AND iterations
        }
        __syncthreads();  // protect h1buf for next iteration's L1 write
    }

    // ======== epilogue: LDS transpose -> fully-coalesced float4 stores ========
    {
        float* sf = (float*)h0buf;           // 64 x 13 floats (3328 B)
        if (l15 < 12) {
            float b3v = b3g[l15];
            #pragma unroll
            for (int r = 0; r < 4; ++r)
                sf[(wave * 16 + q * 4 + r) * 13 + l15] = 0.25f * outacc[r] + b3v;
        }
        __syncthreads();
        if (tid < 192) {
            int ch = tid >> 6, rr = (tid >> 4) & 3, cg = tid & 15;
            int il = rr >> 1, s = rr & 1;
            int ng0 = tile << 6;
            int B2 = ng0 >> 10, pq0 = ng0 & 1023;
            int u2 = B2 / 7, v2 = B2 - 7 * u2;
            int i0b = pq0 >> 5;
            f32x4 v;
            #pragma unroll
            for (int e = 0; e < 4; ++e) {
                int col = cg * 4 + e;
                int j = col >> 1, t2 = col & 1;
                v[e] = sf[(il * 32 + j) * 13 + ch * 4 + s * 2 + t2];
            }
            int row = 2 * (i0b + il) + s;
            *(f32x4*)&out[((ch * 7 + u2) * 7 + v2) * 4096 + row * 64 + cg * 4] = v;
        }
    }
}

extern "C" void kernel_launch(void* const* d_in, const int* in_sizes, int n_in,
                              void* d_out, int out_size, void* d_ws, size_t ws_size,
                              hipStream_t stream)
{
    (void)in_sizes; (void)n_in; (void)out_size; (void)ws_size;
    const float* inp = (const float*)d_in[0];
    const float* W0  = (const float*)d_in[1];
    const float* b0  = (const float*)d_in[2];
    const float* W1  = (const float*)d_in[3];
    const float* b1  = (const float*)d_in[4];
    const float* W2  = (const float*)d_in[5];
    const float* b2  = (const float*)d_in[6];
    const float* W3  = (const float*)d_in[7];
    const float* b3  = (const float*)d_in[8];
    float* out = (float*)d_out;
    unsigned short* wsb = (unsigned short*)d_ws;

    inr_prep<<<668, 256, 0, stream>>>(inp, W0, W1, W2, W3, wsb);
    inr_main<<<784, 256, 0, stream>>>(W0, b0, b1, b2, b3, (const bf16_t*)wsb, out);
}